// Round 1
// baseline (1938.408 us; speedup 1.0000x reference)
//
#include <hip/hip_runtime.h>
#include <hip/hip_bf16.h>
#include <math.h>

// Problem constants
#define BB 2
#define HH 64
#define WW 64
#define DMOD 96
#define DIN 192
#define RR 6
#define NN 16
#define KK 4
#define LL 4096   // H*W

// direction index maps: pos_k(l) gives the hw-position visited at scan step l
// (all are involutions; T and S commute)
__device__ __forceinline__ int pos_k(int k, int l) {
    switch (k) {
        case 0: return l;                                   // hw order
        case 1: return ((l & 63) << 6) | (l >> 6);          // wh order (transpose)
        case 2: return 4095 - l;                            // reversed hw
        default: { int s = 4095 - l; return ((s & 63) << 6) | (s >> 6); } // reversed wh
    }
}

// ---------------- Kernel A: in_proj GEMM ----------------
// xz[b,l,c] = dot(x[b,l,:96], in_proj_w[c,:96]); c<192 -> xc_raw, c>=192 -> z
__global__ __launch_bounds__(256) void k_inproj(const float* __restrict__ x,
                                                const float* __restrict__ W,
                                                float* __restrict__ xc_raw,
                                                float* __restrict__ zbuf) {
    __shared__ float xs[32][DMOD];
    int row0 = blockIdx.x * 32;
    int tid = threadIdx.x;
    for (int i = tid; i < 32 * DMOD; i += 256) {
        xs[i / DMOD][i % DMOD] = x[(size_t)row0 * DMOD + i];
    }
    __syncthreads();
    for (int c = tid; c < 2 * DIN; c += 256) {
        const float* w = W + (size_t)c * DMOD;
        float acc[32];
#pragma unroll
        for (int i = 0; i < 32; i++) acc[i] = 0.f;
        for (int j = 0; j < DMOD; j++) {
            float wv = w[j];
#pragma unroll
            for (int i = 0; i < 32; i++) acc[i] += xs[i][j] * wv;
        }
#pragma unroll
        for (int i = 0; i < 32; i++) {
            int row = row0 + i;
            if (c < DIN) xc_raw[(size_t)row * DIN + c] = acc[i];
            else         zbuf[(size_t)row * DIN + (c - DIN)] = acc[i];
        }
    }
}

// ---------------- Kernel B: depthwise 3x3 conv + bias + SiLU ----------------
// in: xc_raw (b, l, d) channel-last ; out: xc_l (b, l, d) channel-last
__global__ __launch_bounds__(256) void k_conv(const float* __restrict__ xc_raw,
                                              const float* __restrict__ cw,
                                              const float* __restrict__ cb,
                                              float* __restrict__ xc_l) {
    int idx = blockIdx.x * 256 + threadIdx.x;          // B*L*DIN
    if (idx >= BB * LL * DIN) return;
    int d = idx % DIN;
    int l = (idx / DIN) % LL;
    int b = idx / (DIN * LL);
    int h = l >> 6, w = l & 63;
    float acc = cb[d];
#pragma unroll
    for (int dh = -1; dh <= 1; dh++) {
        int hh = h + dh;
        if (hh < 0 || hh >= HH) continue;
#pragma unroll
        for (int dw = -1; dw <= 1; dw++) {
            int ww2 = w + dw;
            if (ww2 < 0 || ww2 >= WW) continue;
            acc += xc_raw[((size_t)b * LL + hh * 64 + ww2) * DIN + d] *
                   cw[d * 9 + (dh + 1) * 3 + (dw + 1)];
        }
    }
    // silu
    float s = acc / (1.f + expf(-acc));
    xc_l[(size_t)idx] = s;
}

// ---------------- Kernel C: x_proj (38 dots) + dt_proj (6->192) + softplus ----------------
// grid: B*K*L blocks of 64 threads
__global__ __launch_bounds__(64) void k_xproj(const float* __restrict__ xc_l,
                                              const float* __restrict__ xpw,   // (K,38,192)
                                              const float* __restrict__ dtw,   // (K,192,6)
                                              const float* __restrict__ dtb,   // (K,192)
                                              float* __restrict__ delta,       // (b,k,l,192)
                                              float* __restrict__ Bsb,         // (b,k,l,16)
                                              float* __restrict__ Csb) {       // (b,k,l,16)
    int blk = blockIdx.x;
    int l = blk & 4095;
    int k = (blk >> 12) & 3;
    int b = blk >> 14;
    int t = threadIdx.x;
    __shared__ float xv[DIN];
    __shared__ float cv[RR + 2 * NN];

    int lp = pos_k(k, l);
    const float* src = xc_l + ((size_t)b * LL + lp) * DIN;
    for (int i = t; i < DIN; i += 64) xv[i] = src[i];
    __syncthreads();

    if (t < RR + 2 * NN) {
        const float* w = xpw + ((size_t)k * (RR + 2 * NN) + t) * DIN;
        float acc = 0.f;
        for (int j = 0; j < DIN; j++) acc += xv[j] * w[j];
        cv[t] = acc;
    }
    __syncthreads();

    size_t base = (size_t)(b * KK + k) * LL + l;
    if (t < NN) Bsb[base * NN + t] = cv[RR + t];
    else if (t < 2 * NN) Csb[base * NN + (t - NN)] = cv[RR + NN + (t - NN)];

    float c0 = cv[0], c1 = cv[1], c2 = cv[2], c3 = cv[3], c4 = cv[4], c5 = cv[5];
    for (int d = t; d < DIN; d += 64) {
        const float* w = dtw + ((size_t)k * DIN + d) * RR;
        float v = dtb[k * DIN + d] + c0 * w[0] + c1 * w[1] + c2 * w[2] +
                  c3 * w[3] + c4 * w[4] + c5 * w[5];
        float sp = (v > 20.f) ? v : log1pf(expf(v));
        delta[base * DIN + d] = sp;
    }
}

// ---------------- Kernel D: selective scan ----------------
// one lane per (b,k,d,n); block = 16 d x 16 n = 256 threads; grid = B*K*12
__global__ __launch_bounds__(256) void k_scan(const float* __restrict__ delta,
                                              const float* __restrict__ Bsb,
                                              const float* __restrict__ Csb,
                                              const float* __restrict__ xc_l,
                                              const float* __restrict__ A_logs, // (K*192,16)
                                              float* __restrict__ y_dir) {      // (b,k,l,192)
    int blk = blockIdx.x;
    int dg = blk % 12;
    int k = (blk / 12) % 4;
    int b = blk / 48;
    int t = threadIdx.x;
    int dl = t >> 4;
    int n = t & 15;
    int d = dg * 16 + dl;

    float An = -expf(A_logs[((size_t)(k * DIN + d)) * NN + n]);
    float h = 0.f;

    size_t bk = (size_t)(b * KK + k) * LL;
    const float* dptr = delta + bk * DIN + d;
    const float* bptr = Bsb + bk * NN + n;
    const float* cptr = Csb + bk * NN + n;
    const float* uptr = xc_l + (size_t)b * LL * DIN + d;
    float* yptr = y_dir + bk * DIN + d;

    // software pipeline: prefetch step l+1 while finishing step l
    float dv = dptr[0];
    float u  = uptr[(size_t)pos_k(k, 0) * DIN];
    float Bn = bptr[0];
    float Cn = cptr[0];
    float dA = expf(dv * An);

    for (int l = 0; l < LL; l++) {
        int ln = (l + 1 < LL) ? (l + 1) : (LL - 1);
        float dv1 = dptr[(size_t)ln * DIN];
        float u1  = uptr[(size_t)pos_k(k, ln) * DIN];
        float B1  = bptr[(size_t)ln * NN];
        float C1  = cptr[(size_t)ln * NN];
        float dA1 = expf(dv1 * An);

        h = dA * h + (dv * u) * Bn;
        float p = h * Cn;
        p += __shfl_xor(p, 1, 64);
        p += __shfl_xor(p, 2, 64);
        p += __shfl_xor(p, 4, 64);
        p += __shfl_xor(p, 8, 64);
        if (n == 0) yptr[(size_t)l * DIN] = p;

        dv = dv1; u = u1; Bn = B1; Cn = C1; dA = dA1;
    }
}

// ---------------- Kernel E: merge 4 directions + Ds*u + LayerNorm + SiLU(z) + out_proj ----------------
// block per (b,hw); 192 threads
__global__ __launch_bounds__(192) void k_out(const float* __restrict__ y_dir,
                                             const float* __restrict__ xc_l,
                                             const float* __restrict__ zbuf,
                                             const float* __restrict__ Ds,     // (K*192,)
                                             const float* __restrict__ g,
                                             const float* __restrict__ be,
                                             const float* __restrict__ Wout,   // (96,192)
                                             float* __restrict__ out) {
    int bl = blockIdx.x;              // b*4096 + hw
    int b = bl >> 12;
    int hw = bl & 4095;
    int t = threadIdx.x;              // d

    __shared__ float yn[DIN];
    __shared__ float red[8];

    float acc = 0.f;
#pragma unroll
    for (int k = 0; k < KK; k++) {
        int lp = pos_k(k, hw);
        acc += y_dir[((size_t)(b * KK + k) * LL + lp) * DIN + t];
    }
    float ds_sum = Ds[t] + Ds[DIN + t] + Ds[2 * DIN + t] + Ds[3 * DIN + t];
    acc += ds_sum * xc_l[(size_t)bl * DIN + t];

    // block reduction (3 waves)
    float s = acc, s2 = acc * acc;
#pragma unroll
    for (int o = 32; o > 0; o >>= 1) {
        s  += __shfl_down(s, o, 64);
        s2 += __shfl_down(s2, o, 64);
    }
    int wid = t >> 6;
    if ((t & 63) == 0) { red[wid] = s; red[4 + wid] = s2; }
    __syncthreads();
    float mean = (red[0] + red[1] + red[2]) * (1.f / DIN);
    float msq  = (red[4] + red[5] + red[6]) * (1.f / DIN);
    float var = msq - mean * mean;
    float rstd = rsqrtf(var + 1e-5f);

    float yv = (acc - mean) * rstd * g[t] + be[t];
    float zv = zbuf[(size_t)bl * DIN + t];
    yv *= zv / (1.f + expf(-zv));
    yn[t] = yv;
    __syncthreads();

    if (t < DMOD) {
        const float* w = Wout + (size_t)t * DIN;
        float o = 0.f;
        for (int j = 0; j < DIN; j++) o += yn[j] * w[j];
        out[(size_t)bl * DMOD + t] = o;
    }
}

extern "C" void kernel_launch(void* const* d_in, const int* in_sizes, int n_in,
                              void* d_out, int out_size, void* d_ws, size_t ws_size,
                              hipStream_t stream) {
    const float* x        = (const float*)d_in[0];
    const float* in_proj_w= (const float*)d_in[1];
    const float* conv_w   = (const float*)d_in[2];
    const float* conv_b   = (const float*)d_in[3];
    const float* x_proj_w = (const float*)d_in[4];
    const float* dt_proj_w= (const float*)d_in[5];
    const float* dt_proj_b= (const float*)d_in[6];
    const float* A_logs   = (const float*)d_in[7];
    const float* Ds       = (const float*)d_in[8];
    const float* out_g    = (const float*)d_in[9];
    const float* out_b    = (const float*)d_in[10];
    const float* out_proj_w=(const float*)d_in[11];
    float* out = (float*)d_out;

    // workspace layout (floats)
    float* ws = (float*)d_ws;
    const size_t BL   = (size_t)BB * LL;          // 8192
    float* xc_raw = ws;                           // BL*192
    float* zbuf   = xc_raw + BL * DIN;            // BL*192
    float* xc_l   = zbuf + BL * DIN;              // BL*192
    float* delta  = xc_l + BL * DIN;              // B*K*L*192
    float* Bsb    = delta + (size_t)BB * KK * LL * DIN;   // B*K*L*16
    float* Csb    = Bsb + (size_t)BB * KK * LL * NN;
    float* y_dir  = Csb + (size_t)BB * KK * LL * NN;      // B*K*L*192

    // A: in_proj  (8192 rows / 32 per block)
    k_inproj<<<BL / 32, 256, 0, stream>>>(x, in_proj_w, xc_raw, zbuf);
    // B: conv+silu
    k_conv<<<(BB * LL * DIN + 255) / 256, 256, 0, stream>>>(xc_raw, conv_w, conv_b, xc_l);
    // C: x_proj + dt_proj + softplus
    k_xproj<<<BB * KK * LL, 64, 0, stream>>>(xc_l, x_proj_w, dt_proj_w, dt_proj_b,
                                             delta, Bsb, Csb);
    // D: selective scan
    k_scan<<<BB * KK * (DIN / 16), 256, 0, stream>>>(delta, Bsb, Csb, xc_l, A_logs, y_dir);
    // E: merge + LN + gate + out_proj
    k_out<<<BB * LL, 192, 0, stream>>>(y_dir, xc_l, zbuf, Ds, out_g, out_b, out_proj_w, out);
}

// Round 2
// 504.510 us; speedup vs baseline: 3.8422x; 3.8422x over previous
//
#include <hip/hip_runtime.h>
#include <hip/hip_bf16.h>
#include <math.h>

// Problem constants
#define BB 2
#define HH 64
#define WW 64
#define DMOD 96
#define DIN 192
#define RR 6
#define NN 16
#define KK 4
#define LL 4096   // H*W
#define NC 64     // number of scan chunks
#define CL 64     // chunk length (NC*CL == LL)
#define BKDN (BB * KK * DIN * NN)   // 24576 scan states

// direction index maps: pos_k(l) gives the hw-position visited at scan step l
// (all are involutions; T and S commute)
__device__ __forceinline__ int pos_k(int k, int l) {
    switch (k) {
        case 0: return l;                                   // hw order
        case 1: return ((l & 63) << 6) | (l >> 6);          // wh order (transpose)
        case 2: return 4095 - l;                            // reversed hw
        default: { int s = 4095 - l; return ((s & 63) << 6) | (s >> 6); } // reversed wh
    }
}

// ---------------- Kernel A: in_proj GEMM ----------------
__global__ __launch_bounds__(256) void k_inproj(const float* __restrict__ x,
                                                const float* __restrict__ W,
                                                float* __restrict__ xc_raw,
                                                float* __restrict__ zbuf) {
    __shared__ float xs[32][DMOD];
    int row0 = blockIdx.x * 32;
    int tid = threadIdx.x;
    for (int i = tid; i < 32 * DMOD; i += 256) {
        xs[i / DMOD][i % DMOD] = x[(size_t)row0 * DMOD + i];
    }
    __syncthreads();
    for (int c = tid; c < 2 * DIN; c += 256) {
        const float* w = W + (size_t)c * DMOD;
        float acc[32];
#pragma unroll
        for (int i = 0; i < 32; i++) acc[i] = 0.f;
        for (int j = 0; j < DMOD; j++) {
            float wv = w[j];
#pragma unroll
            for (int i = 0; i < 32; i++) acc[i] += xs[i][j] * wv;
        }
#pragma unroll
        for (int i = 0; i < 32; i++) {
            int row = row0 + i;
            if (c < DIN) xc_raw[(size_t)row * DIN + c] = acc[i];
            else         zbuf[(size_t)row * DIN + (c - DIN)] = acc[i];
        }
    }
}

// ---------------- Kernel B: depthwise 3x3 conv + bias + SiLU ----------------
__global__ __launch_bounds__(256) void k_conv(const float* __restrict__ xc_raw,
                                              const float* __restrict__ cw,
                                              const float* __restrict__ cb,
                                              float* __restrict__ xc_l) {
    int idx = blockIdx.x * 256 + threadIdx.x;          // B*L*DIN
    if (idx >= BB * LL * DIN) return;
    int d = idx % DIN;
    int l = (idx / DIN) % LL;
    int b = idx / (DIN * LL);
    int h = l >> 6, w = l & 63;
    float acc = cb[d];
#pragma unroll
    for (int dh = -1; dh <= 1; dh++) {
        int hh = h + dh;
        if (hh < 0 || hh >= HH) continue;
#pragma unroll
        for (int dw = -1; dw <= 1; dw++) {
            int ww2 = w + dw;
            if (ww2 < 0 || ww2 >= WW) continue;
            acc += xc_raw[((size_t)b * LL + hh * 64 + ww2) * DIN + d] *
                   cw[d * 9 + (dh + 1) * 3 + (dw + 1)];
        }
    }
    float s = acc / (1.f + expf(-acc));
    xc_l[(size_t)idx] = s;
}

// ---------------- Kernel C: x_proj (38 dots) + dt_proj (6->192) + softplus ----------------
__global__ __launch_bounds__(64) void k_xproj(const float* __restrict__ xc_l,
                                              const float* __restrict__ xpw,   // (K,38,192)
                                              const float* __restrict__ dtw,   // (K,192,6)
                                              const float* __restrict__ dtb,   // (K,192)
                                              float* __restrict__ delta,       // (b,k,l,192)
                                              float* __restrict__ Bsb,         // (b,k,l,16)
                                              float* __restrict__ Csb) {       // (b,k,l,16)
    int blk = blockIdx.x;
    int l = blk & 4095;
    int k = (blk >> 12) & 3;
    int b = blk >> 14;
    int t = threadIdx.x;
    __shared__ float xv[DIN];
    __shared__ float cv[RR + 2 * NN];

    int lp = pos_k(k, l);
    const float* src = xc_l + ((size_t)b * LL + lp) * DIN;
    for (int i = t; i < DIN; i += 64) xv[i] = src[i];
    __syncthreads();

    if (t < RR + 2 * NN) {
        const float* w = xpw + ((size_t)k * (RR + 2 * NN) + t) * DIN;
        float acc = 0.f;
        for (int j = 0; j < DIN; j++) acc += xv[j] * w[j];
        cv[t] = acc;
    }
    __syncthreads();

    size_t base = (size_t)(b * KK + k) * LL + l;
    if (t < NN) Bsb[base * NN + t] = cv[RR + t];
    else if (t < 2 * NN) Csb[base * NN + (t - NN)] = cv[RR + NN + (t - NN)];

    float c0 = cv[0], c1 = cv[1], c2 = cv[2], c3 = cv[3], c4 = cv[4], c5 = cv[5];
    for (int d = t; d < DIN; d += 64) {
        const float* w = dtw + ((size_t)k * DIN + d) * RR;
        float v = dtb[k * DIN + d] + c0 * w[0] + c1 * w[1] + c2 * w[2] +
                  c3 * w[3] + c4 * w[4] + c5 * w[5];
        float sp = (v > 20.f) ? v : log1pf(expf(v));
        delta[base * DIN + d] = sp;
    }
}

// ---------------- Kernel D1: per-chunk local scan (zero init) ----------------
// block = 256 (16 d x 16 n); grid = B*K*12*NC
// outputs per state per chunk: P = prod(dA), E = local end state
__global__ __launch_bounds__(256) void k_scan1(const float* __restrict__ delta,
                                               const float* __restrict__ Bsb,
                                               const float* __restrict__ xc_l,
                                               const float* __restrict__ A_logs,
                                               float* __restrict__ P,
                                               float* __restrict__ E) {
    int blk = blockIdx.x;
    int c = blk % NC;
    int rest = blk / NC;
    int dg = rest % 12;
    int k = (rest / 12) % 4;
    int b = rest / 48;
    int t = threadIdx.x;
    int dl = t >> 4;
    int n = t & 15;
    int d = dg * 16 + dl;

    float An = -expf(A_logs[((size_t)(k * DIN + d)) * NN + n]);
    size_t bk = (size_t)(b * KK + k) * LL;
    const float* dptr = delta + bk * DIN + d;
    const float* bptr = Bsb + bk * NN + n;
    const float* uptr = xc_l + (size_t)b * LL * DIN + d;

    float h = 0.f, Pp = 1.f;
    int l0 = c * CL;
    for (int l = l0; l < l0 + CL; l++) {
        float dv = dptr[(size_t)l * DIN];
        float u  = uptr[(size_t)pos_k(k, l) * DIN];
        float Bn = bptr[(size_t)l * NN];
        float dA = expf(dv * An);
        Pp *= dA;
        h = dA * h + (dv * u) * Bn;
    }
    size_t st = ((size_t)(b * KK + k) * DIN + d) * NN + n;
    P[(size_t)c * BKDN + st] = Pp;
    E[(size_t)c * BKDN + st] = h;
}

// ---------------- Kernel D2: inter-chunk recurrence ----------------
// one thread per state; E[c] is overwritten in place with Hin[c] (state entering chunk c)
__global__ __launch_bounds__(256) void k_scan2(const float* __restrict__ P,
                                               float* __restrict__ E) {
    int gid = blockIdx.x * 256 + threadIdx.x;
    if (gid >= BKDN) return;
    float h = 0.f;
    for (int c = 0; c < NC; c++) {
        size_t o = (size_t)c * BKDN + gid;
        float p = P[o];
        float e = E[o];
        E[o] = h;            // true initial state for chunk c
        h = p * h + e;       // end state of chunk c
    }
}

// ---------------- Kernel D3: per-chunk rescan with true init; y written over delta ----------------
__global__ __launch_bounds__(256) void k_scan3(float* __restrict__ delta,      // in: delta, out: y
                                               const float* __restrict__ Bsb,
                                               const float* __restrict__ Csb,
                                               const float* __restrict__ xc_l,
                                               const float* __restrict__ A_logs,
                                               const float* __restrict__ Hin) {
    int blk = blockIdx.x;
    int c = blk % NC;
    int rest = blk / NC;
    int dg = rest % 12;
    int k = (rest / 12) % 4;
    int b = rest / 48;
    int t = threadIdx.x;
    int dl = t >> 4;
    int n = t & 15;
    int d = dg * 16 + dl;

    float An = -expf(A_logs[((size_t)(k * DIN + d)) * NN + n]);
    size_t bk = (size_t)(b * KK + k) * LL;
    float* dptr = delta + bk * DIN + d;
    const float* bptr = Bsb + bk * NN + n;
    const float* cptr = Csb + bk * NN + n;
    const float* uptr = xc_l + (size_t)b * LL * DIN + d;

    size_t st = ((size_t)(b * KK + k) * DIN + d) * NN + n;
    float h = Hin[(size_t)c * BKDN + st];

    int l0 = c * CL;
    for (int l = l0; l < l0 + CL; l++) {
        float dv = dptr[(size_t)l * DIN];
        float u  = uptr[(size_t)pos_k(k, l) * DIN];
        float Bn = bptr[(size_t)l * NN];
        float Cn = cptr[(size_t)l * NN];
        float dA = expf(dv * An);
        h = dA * h + (dv * u) * Bn;
        float p = h * Cn;
        p += __shfl_xor(p, 1, 64);
        p += __shfl_xor(p, 2, 64);
        p += __shfl_xor(p, 4, 64);
        p += __shfl_xor(p, 8, 64);
        if (n == 0) dptr[(size_t)l * DIN] = p;   // in-place: y over delta
    }
}

// ---------------- Kernel E: merge 4 directions + Ds*u + LayerNorm + SiLU(z) + out_proj ----------------
__global__ __launch_bounds__(192) void k_out(const float* __restrict__ y_dir,
                                             const float* __restrict__ xc_l,
                                             const float* __restrict__ zbuf,
                                             const float* __restrict__ Ds,
                                             const float* __restrict__ g,
                                             const float* __restrict__ be,
                                             const float* __restrict__ Wout,
                                             float* __restrict__ out) {
    int bl = blockIdx.x;              // b*4096 + hw
    int b = bl >> 12;
    int hw = bl & 4095;
    int t = threadIdx.x;              // d

    __shared__ float yn[DIN];
    __shared__ float red[8];

    float acc = 0.f;
#pragma unroll
    for (int k = 0; k < KK; k++) {
        int lp = pos_k(k, hw);
        acc += y_dir[((size_t)(b * KK + k) * LL + lp) * DIN + t];
    }
    float ds_sum = Ds[t] + Ds[DIN + t] + Ds[2 * DIN + t] + Ds[3 * DIN + t];
    acc += ds_sum * xc_l[(size_t)bl * DIN + t];

    float s = acc, s2 = acc * acc;
#pragma unroll
    for (int o = 32; o > 0; o >>= 1) {
        s  += __shfl_down(s, o, 64);
        s2 += __shfl_down(s2, o, 64);
    }
    int wid = t >> 6;
    if ((t & 63) == 0) { red[wid] = s; red[4 + wid] = s2; }
    __syncthreads();
    float mean = (red[0] + red[1] + red[2]) * (1.f / DIN);
    float msq  = (red[4] + red[5] + red[6]) * (1.f / DIN);
    float var = msq - mean * mean;
    float rstd = rsqrtf(var + 1e-5f);

    float yv = (acc - mean) * rstd * g[t] + be[t];
    float zv = zbuf[(size_t)bl * DIN + t];
    yv *= zv / (1.f + expf(-zv));
    yn[t] = yv;
    __syncthreads();

    if (t < DMOD) {
        const float* w = Wout + (size_t)t * DIN;
        float o = 0.f;
        for (int j = 0; j < DIN; j++) o += yn[j] * w[j];
        out[(size_t)bl * DMOD + t] = o;
    }
}

extern "C" void kernel_launch(void* const* d_in, const int* in_sizes, int n_in,
                              void* d_out, int out_size, void* d_ws, size_t ws_size,
                              hipStream_t stream) {
    const float* x        = (const float*)d_in[0];
    const float* in_proj_w= (const float*)d_in[1];
    const float* conv_w   = (const float*)d_in[2];
    const float* conv_b   = (const float*)d_in[3];
    const float* x_proj_w = (const float*)d_in[4];
    const float* dt_proj_w= (const float*)d_in[5];
    const float* dt_proj_b= (const float*)d_in[6];
    const float* A_logs   = (const float*)d_in[7];
    const float* Ds       = (const float*)d_in[8];
    const float* out_g    = (const float*)d_in[9];
    const float* out_b    = (const float*)d_in[10];
    const float* out_proj_w=(const float*)d_in[11];
    float* out = (float*)d_out;

    // workspace layout (floats)  — total ~57 MB (< the 73 MB that round-0 used OK)
    float* ws = (float*)d_ws;
    const size_t BL = (size_t)BB * LL;                    // 8192
    float* xc_raw = ws;                                   // BL*192
    float* zbuf   = xc_raw + BL * DIN;                    // BL*192
    float* xc_l   = zbuf + BL * DIN;                      // BL*192
    float* delta  = xc_l + BL * DIN;                      // B*K*L*192  (becomes y in pass 3)
    float* Bsb    = delta + (size_t)BB * KK * LL * DIN;   // B*K*L*16
    float* Csb    = Bsb + (size_t)BB * KK * LL * NN;      // B*K*L*16
    float* Pbuf   = Csb + (size_t)BB * KK * LL * NN;      // NC*BKDN
    float* Ebuf   = Pbuf + (size_t)NC * BKDN;             // NC*BKDN

    k_inproj<<<BL / 32, 256, 0, stream>>>(x, in_proj_w, xc_raw, zbuf);
    k_conv<<<(BB * LL * DIN + 255) / 256, 256, 0, stream>>>(xc_raw, conv_w, conv_b, xc_l);
    k_xproj<<<BB * KK * LL, 64, 0, stream>>>(xc_l, x_proj_w, dt_proj_w, dt_proj_b,
                                             delta, Bsb, Csb);
    // chunked selective scan
    k_scan1<<<BB * KK * 12 * NC, 256, 0, stream>>>(delta, Bsb, xc_l, A_logs, Pbuf, Ebuf);
    k_scan2<<<(BKDN + 255) / 256, 256, 0, stream>>>(Pbuf, Ebuf);
    k_scan3<<<BB * KK * 12 * NC, 256, 0, stream>>>(delta, Bsb, Csb, xc_l, A_logs, Ebuf);
    k_out<<<BB * LL, 192, 0, stream>>>(delta, xc_l, zbuf, Ds, out_g, out_b, out_proj_w, out);
}

// Round 3
// 256.308 us; speedup vs baseline: 7.5628x; 1.9684x over previous
//
#include <hip/hip_runtime.h>
#include <hip/hip_bf16.h>
#include <math.h>

// Problem constants
#define BB 2
#define HH 64
#define WW 64
#define DMOD 96
#define DIN 192
#define RR 6
#define NN 16
#define KK 4
#define LL 4096   // H*W
#define NC 128    // number of scan chunks
#define CL 32     // chunk length (NC*CL == LL)
#define BKD (BB * KK * DIN)         // 1536
#define BKDN (BKD * NN)             // 24576 scan states

// direction index maps: pos_k(l) gives the hw-position visited at scan step l
__device__ __forceinline__ int pos_k(int k, int l) {
    switch (k) {
        case 0: return l;
        case 1: return ((l & 63) << 6) | (l >> 6);
        case 2: return 4095 - l;
        default: { int s = 4095 - l; return ((s & 63) << 6) | (s >> 6); }
    }
}

// ---------------- Kernel A: in_proj GEMM ----------------
__global__ __launch_bounds__(256) void k_inproj(const float* __restrict__ x,
                                                const float* __restrict__ W,
                                                float* __restrict__ xc_raw,
                                                float* __restrict__ zbuf) {
    __shared__ float xs[32][DMOD];
    int row0 = blockIdx.x * 32;
    int tid = threadIdx.x;
    for (int i = tid; i < 32 * DMOD; i += 256) {
        xs[i / DMOD][i % DMOD] = x[(size_t)row0 * DMOD + i];
    }
    __syncthreads();
    for (int c = tid; c < 2 * DIN; c += 256) {
        const float* w = W + (size_t)c * DMOD;
        float acc[32];
#pragma unroll
        for (int i = 0; i < 32; i++) acc[i] = 0.f;
        for (int j = 0; j < DMOD; j++) {
            float wv = w[j];
#pragma unroll
            for (int i = 0; i < 32; i++) acc[i] += xs[i][j] * wv;
        }
#pragma unroll
        for (int i = 0; i < 32; i++) {
            int row = row0 + i;
            if (c < DIN) xc_raw[(size_t)row * DIN + c] = acc[i];
            else         zbuf[(size_t)row * DIN + (c - DIN)] = acc[i];
        }
    }
}

// ---------------- Kernel B: depthwise 3x3 conv + bias + SiLU ----------------
__global__ __launch_bounds__(256) void k_conv(const float* __restrict__ xc_raw,
                                              const float* __restrict__ cw,
                                              const float* __restrict__ cb,
                                              float* __restrict__ xc_l) {
    int idx = blockIdx.x * 256 + threadIdx.x;          // B*L*DIN
    if (idx >= BB * LL * DIN) return;
    int d = idx % DIN;
    int l = (idx / DIN) % LL;
    int b = idx / (DIN * LL);
    int h = l >> 6, w = l & 63;
    float acc = cb[d];
#pragma unroll
    for (int dh = -1; dh <= 1; dh++) {
        int hh = h + dh;
        if (hh < 0 || hh >= HH) continue;
#pragma unroll
        for (int dw = -1; dw <= 1; dw++) {
            int ww2 = w + dw;
            if (ww2 < 0 || ww2 >= WW) continue;
            acc += xc_raw[((size_t)b * LL + hh * 64 + ww2) * DIN + d] *
                   cw[d * 9 + (dh + 1) * 3 + (dw + 1)];
        }
    }
    float s = acc / (1.f + __expf(-acc));
    xc_l[(size_t)idx] = s;
}

// ---------------- Kernel C: x_proj GEMM tile + fused dt_proj + softplus ----------------
// grid = B*K*(LL/32) blocks of 192 threads; each block: 32 scan-rows of direction k
__global__ __launch_bounds__(192) void k_xproj(const float* __restrict__ xc_l,
                                               const float* __restrict__ xpw,   // (K,38,192)
                                               const float* __restrict__ dtw,   // (K,192,6)
                                               const float* __restrict__ dtb,   // (K,192)
                                               float* __restrict__ delta,       // (bk,l,192)
                                               float* __restrict__ Bsb,         // (bk,l,16)
                                               float* __restrict__ Csb) {       // (bk,l,16)
    __shared__ float xs[32][193];     // padded: stride 193 breaks 192-stride bank aliasing
    __shared__ float cvs[38 * 33];    // cvs[c][i] at c*33+i (padded)

    int tile = blockIdx.x & 127;
    int k = (blockIdx.x >> 7) & 3;
    int b = blockIdx.x >> 9;
    int bk = b * KK + k;
    int l0 = tile * 32;
    int t = threadIdx.x;

    // stage 32 rows (in scan order for direction k)
    for (int i = 0; i < 32; i++) {
        int lp = pos_k(k, l0 + i);
        xs[i][t] = xc_l[((size_t)b * LL + lp) * DIN + t];
    }
    __syncthreads();

    // GEMM: 38 cols x 32 rows, thread = (rowgroup rg of 8, col c)
    {
        int rg = t / 48;          // 0..3
        int c = t % 48;           // 0..47, active c<38
        if (c < 38) {
            const float* w = xpw + ((size_t)k * 38 + c) * DIN;
            int i0 = rg * 8;
            float acc[8];
#pragma unroll
            for (int r = 0; r < 8; r++) acc[r] = 0.f;
            for (int j = 0; j < DIN; j++) {
                float wv = w[j];
#pragma unroll
                for (int r = 0; r < 8; r++) acc[r] += xs[i0 + r][j] * wv;
            }
#pragma unroll
            for (int r = 0; r < 8; r++) cvs[c * 33 + i0 + r] = acc[r];
        }
    }
    __syncthreads();

    // write B and C (cols 6..21 and 22..37)
    for (int idx = t; idx < 512; idx += 192) {
        int i = idx >> 4, n = idx & 15;
        size_t o = ((size_t)bk * LL + (l0 + i)) * NN + n;
        Bsb[o] = cvs[(6 + n) * 33 + i];
        Csb[o] = cvs[(22 + n) * 33 + i];
    }

    // delta: d = t fixed, loop rows
    {
        const float* dwp = dtw + ((size_t)k * DIN + t) * RR;
        float dw0 = dwp[0], dw1 = dwp[1], dw2 = dwp[2],
              dw3 = dwp[3], dw4 = dwp[4], dw5 = dwp[5];
        float bias = dtb[k * DIN + t];
        for (int i = 0; i < 32; i++) {
            float v = bias + cvs[0 * 33 + i] * dw0 + cvs[1 * 33 + i] * dw1 +
                      cvs[2 * 33 + i] * dw2 + cvs[3 * 33 + i] * dw3 +
                      cvs[4 * 33 + i] * dw4 + cvs[5 * 33 + i] * dw5;
            float sp = (v > 20.f) ? v : __logf(1.f + __expf(v));
            delta[((size_t)bk * LL + (l0 + i)) * DIN + t] = sp;
        }
    }
}

// ---------------- Kernel D1: per-chunk local scan, 16 states/thread ----------------
// grid = B*K*NC blocks of 192 threads (thread = d)
__global__ __launch_bounds__(192) void k_scan1(const float* __restrict__ delta,
                                               const float* __restrict__ Bsb,
                                               const float* __restrict__ xc_l,
                                               const float* __restrict__ A_logs,
                                               float* __restrict__ Sbuf,   // (NC, BKD)
                                               float* __restrict__ Ebuf) { // (NC, BKDN)
    __shared__ float4 Bs4[CL][4];
    int c = blockIdx.x % NC;
    int bk = blockIdx.x / NC;
    int k = bk % KK;
    int b = bk / KK;
    int t = threadIdx.x;                 // d

    // stage B chunk: CL*16 floats = 128 float4
    {
        const float4* src = (const float4*)(Bsb + ((size_t)bk * LL + c * CL) * NN);
        if (t < CL * 4) ((float4*)Bs4)[t] = src[t];
    }

    float An[NN];
    {
        const float4* ap = (const float4*)(A_logs + ((size_t)(k * DIN + t)) * NN);
#pragma unroll
        for (int q = 0; q < 4; q++) {
            float4 a4 = ap[q];
            An[q * 4 + 0] = -__expf(a4.x);
            An[q * 4 + 1] = -__expf(a4.y);
            An[q * 4 + 2] = -__expf(a4.z);
            An[q * 4 + 3] = -__expf(a4.w);
        }
    }
    __syncthreads();

    const float* dp = delta + ((size_t)bk * LL + c * CL) * DIN + t;
    const float* up = xc_l + (size_t)b * LL * DIN + t;
    int l0 = c * CL;

    float h[NN];
#pragma unroll
    for (int n = 0; n < NN; n++) h[n] = 0.f;
    float S = 0.f;

    float dv = dp[0];
    float u  = up[(size_t)pos_k(k, l0) * DIN];
    for (int li = 0; li < CL; li++) {
        int ln = (li + 1 < CL) ? li + 1 : li;
        float dvn = dp[(size_t)ln * DIN];
        float un  = up[(size_t)pos_k(k, l0 + ln) * DIN];
        S += dv;
        float du = dv * u;
#pragma unroll
        for (int q = 0; q < 4; q++) {
            float4 Bq = Bs4[li][q];
            h[q*4+0] = __expf(dv * An[q*4+0]) * h[q*4+0] + du * Bq.x;
            h[q*4+1] = __expf(dv * An[q*4+1]) * h[q*4+1] + du * Bq.y;
            h[q*4+2] = __expf(dv * An[q*4+2]) * h[q*4+2] + du * Bq.z;
            h[q*4+3] = __expf(dv * An[q*4+3]) * h[q*4+3] + du * Bq.w;
        }
        dv = dvn; u = un;
    }

    Sbuf[(size_t)c * BKD + bk * DIN + t] = S;
    float4* eo = (float4*)(Ebuf + (size_t)c * BKDN + ((size_t)(bk * DIN + t)) * NN);
#pragma unroll
    for (int q = 0; q < 4; q++) {
        float4 v;
        v.x = h[q*4+0]; v.y = h[q*4+1]; v.z = h[q*4+2]; v.w = h[q*4+3];
        eo[q] = v;
    }
}

// ---------------- Kernel D2: inter-chunk recurrence (thread per state) ----------------
__global__ __launch_bounds__(256) void k_scan2(const float* __restrict__ Sbuf,
                                               const float* __restrict__ A_logs,
                                               float* __restrict__ Ebuf) {
    int gid = blockIdx.x * 256 + threadIdx.x;
    if (gid >= BKDN) return;
    int bkd = gid >> 4;
    int n = gid & 15;
    int d = bkd % DIN;
    int k = (bkd / DIN) % KK;
    float An = -__expf(A_logs[((size_t)(k * DIN + d)) * NN + n]);
    float h = 0.f;
    for (int c = 0; c < NC; c++) {
        float S = Sbuf[(size_t)c * BKD + bkd];
        float P = __expf(An * S);
        size_t o = (size_t)c * BKDN + gid;
        float e = Ebuf[o];
        Ebuf[o] = h;          // true initial state entering chunk c
        h = P * h + e;
    }
}

// ---------------- Kernel D3: per-chunk rescan + y (in place over delta) ----------------
__global__ __launch_bounds__(192) void k_scan3(float* __restrict__ delta,    // in: delta, out: y
                                               const float* __restrict__ Bsb,
                                               const float* __restrict__ Csb,
                                               const float* __restrict__ xc_l,
                                               const float* __restrict__ A_logs,
                                               const float* __restrict__ Ebuf) {
    __shared__ float4 Bs4[CL][4];
    __shared__ float4 Cs4[CL][4];
    int c = blockIdx.x % NC;
    int bk = blockIdx.x / NC;
    int k = bk % KK;
    int b = bk / KK;
    int t = threadIdx.x;

    {
        const float4* srcB = (const float4*)(Bsb + ((size_t)bk * LL + c * CL) * NN);
        const float4* srcC = (const float4*)(Csb + ((size_t)bk * LL + c * CL) * NN);
        if (t < CL * 4) {
            ((float4*)Bs4)[t] = srcB[t];
            ((float4*)Cs4)[t] = srcC[t];
        }
    }

    float An[NN];
    {
        const float4* ap = (const float4*)(A_logs + ((size_t)(k * DIN + t)) * NN);
#pragma unroll
        for (int q = 0; q < 4; q++) {
            float4 a4 = ap[q];
            An[q * 4 + 0] = -__expf(a4.x);
            An[q * 4 + 1] = -__expf(a4.y);
            An[q * 4 + 2] = -__expf(a4.z);
            An[q * 4 + 3] = -__expf(a4.w);
        }
    }

    float h[NN];
    {
        const float4* ei = (const float4*)(Ebuf + (size_t)c * BKDN + ((size_t)(bk * DIN + t)) * NN);
#pragma unroll
        for (int q = 0; q < 4; q++) {
            float4 v = ei[q];
            h[q*4+0] = v.x; h[q*4+1] = v.y; h[q*4+2] = v.z; h[q*4+3] = v.w;
        }
    }
    __syncthreads();

    float* dp = delta + ((size_t)bk * LL + c * CL) * DIN + t;
    const float* up = xc_l + (size_t)b * LL * DIN + t;
    int l0 = c * CL;

    float dv = dp[0];
    float u  = up[(size_t)pos_k(k, l0) * DIN];
    for (int li = 0; li < CL; li++) {
        int ln = (li + 1 < CL) ? li + 1 : li;
        float dvn = dp[(size_t)ln * DIN];
        float un  = up[(size_t)pos_k(k, l0 + ln) * DIN];
        float du = dv * u;
        float p = 0.f;
#pragma unroll
        for (int q = 0; q < 4; q++) {
            float4 Bq = Bs4[li][q];
            float4 Cq = Cs4[li][q];
            h[q*4+0] = __expf(dv * An[q*4+0]) * h[q*4+0] + du * Bq.x;
            h[q*4+1] = __expf(dv * An[q*4+1]) * h[q*4+1] + du * Bq.y;
            h[q*4+2] = __expf(dv * An[q*4+2]) * h[q*4+2] + du * Bq.z;
            h[q*4+3] = __expf(dv * An[q*4+3]) * h[q*4+3] + du * Bq.w;
            p += h[q*4+0] * Cq.x + h[q*4+1] * Cq.y + h[q*4+2] * Cq.z + h[q*4+3] * Cq.w;
        }
        dp[(size_t)li * DIN] = p;      // y over delta (this thread is sole reader of this slot)
        dv = dvn; u = un;
    }
}

// ---------------- Kernel E: merge + Ds*u + LayerNorm + SiLU(z) + out_proj ----------------
__global__ __launch_bounds__(192) void k_out(const float* __restrict__ y_dir,
                                             const float* __restrict__ xc_l,
                                             const float* __restrict__ zbuf,
                                             const float* __restrict__ Ds,
                                             const float* __restrict__ g,
                                             const float* __restrict__ be,
                                             const float* __restrict__ Wout,
                                             float* __restrict__ out) {
    int bl = blockIdx.x;              // b*4096 + hw
    int b = bl >> 12;
    int hw = bl & 4095;
    int t = threadIdx.x;              // d

    __shared__ float yn[DIN];
    __shared__ float red[8];
    __shared__ float par[DMOD * 2];

    float acc = 0.f;
#pragma unroll
    for (int k = 0; k < KK; k++) {
        int lp = pos_k(k, hw);
        acc += y_dir[((size_t)(b * KK + k) * LL + lp) * DIN + t];
    }
    float ds_sum = Ds[t] + Ds[DIN + t] + Ds[2 * DIN + t] + Ds[3 * DIN + t];
    acc += ds_sum * xc_l[(size_t)bl * DIN + t];

    float s = acc, s2 = acc * acc;
#pragma unroll
    for (int o = 32; o > 0; o >>= 1) {
        s  += __shfl_down(s, o, 64);
        s2 += __shfl_down(s2, o, 64);
    }
    int wid = t >> 6;
    if ((t & 63) == 0) { red[wid] = s; red[4 + wid] = s2; }
    __syncthreads();
    float mean = (red[0] + red[1] + red[2]) * (1.f / DIN);
    float msq  = (red[4] + red[5] + red[6]) * (1.f / DIN);
    float var = msq - mean * mean;
    float rstd = rsqrtf(var + 1e-5f);

    float yv = (acc - mean) * rstd * g[t] + be[t];
    float zv = zbuf[(size_t)bl * DIN + t];
    yv *= zv / (1.f + __expf(-zv));
    yn[t] = yv;
    __syncthreads();

    // out_proj: 96 cols, 2 threads per col (halves of K=192)
    {
        int col = t % DMOD;
        int half = t / DMOD;
        const float* w = Wout + (size_t)col * DIN + half * 96;
        const float* y = yn + half * 96;
        float o = 0.f;
        for (int j = 0; j < 96; j++) o += y[j] * w[j];
        par[col * 2 + half] = o;
    }
    __syncthreads();
    if (t < DMOD) out[(size_t)bl * DMOD + t] = par[t * 2] + par[t * 2 + 1];
}

extern "C" void kernel_launch(void* const* d_in, const int* in_sizes, int n_in,
                              void* d_out, int out_size, void* d_ws, size_t ws_size,
                              hipStream_t stream) {
    const float* x        = (const float*)d_in[0];
    const float* in_proj_w= (const float*)d_in[1];
    const float* conv_w   = (const float*)d_in[2];
    const float* conv_b   = (const float*)d_in[3];
    const float* x_proj_w = (const float*)d_in[4];
    const float* dt_proj_w= (const float*)d_in[5];
    const float* dt_proj_b= (const float*)d_in[6];
    const float* A_logs   = (const float*)d_in[7];
    const float* Ds       = (const float*)d_in[8];
    const float* out_g    = (const float*)d_in[9];
    const float* out_b    = (const float*)d_in[10];
    const float* out_proj_w=(const float*)d_in[11];
    float* out = (float*)d_out;

    // workspace layout (floats) — ~62 MB total
    float* ws = (float*)d_ws;
    const size_t BL = (size_t)BB * LL;                    // 8192
    float* xc_raw = ws;                                   // BL*192
    float* zbuf   = xc_raw + BL * DIN;                    // BL*192
    float* xc_l   = zbuf + BL * DIN;                      // BL*192
    float* delta  = xc_l + BL * DIN;                      // B*K*L*192 (becomes y)
    float* Bsb    = delta + (size_t)BB * KK * LL * DIN;   // B*K*L*16
    float* Csb    = Bsb + (size_t)BB * KK * LL * NN;      // B*K*L*16
    float* Ebuf   = Csb + (size_t)BB * KK * LL * NN;      // NC*BKDN
    float* Sbuf   = Ebuf + (size_t)NC * BKDN;             // NC*BKD

    k_inproj<<<BL / 32, 256, 0, stream>>>(x, in_proj_w, xc_raw, zbuf);
    k_conv<<<(BB * LL * DIN + 255) / 256, 256, 0, stream>>>(xc_raw, conv_w, conv_b, xc_l);
    k_xproj<<<BB * KK * (LL / 32), 192, 0, stream>>>(xc_l, x_proj_w, dt_proj_w, dt_proj_b,
                                                     delta, Bsb, Csb);
    k_scan1<<<BB * KK * NC, 192, 0, stream>>>(delta, Bsb, xc_l, A_logs, Sbuf, Ebuf);
    k_scan2<<<(BKDN + 255) / 256, 256, 0, stream>>>(Sbuf, A_logs, Ebuf);
    k_scan3<<<BB * KK * NC, 192, 0, stream>>>(delta, Bsb, Csb, xc_l, A_logs, Ebuf);
    k_out<<<BB * LL, 192, 0, stream>>>(delta, xc_l, zbuf, Ds, out_g, out_b, out_proj_w, out);
}

// Round 4
// 254.024 us; speedup vs baseline: 7.6308x; 1.0090x over previous
//
#include <hip/hip_runtime.h>
#include <hip/hip_bf16.h>
#include <math.h>

// Problem constants
#define BB 2
#define HH 64
#define WW 64
#define DMOD 96
#define DIN 192
#define RR 6
#define NN 16
#define KK 4
#define LL 4096   // H*W
#define NC 128    // number of scan chunks
#define CL 32     // chunk length (NC*CL == LL)
#define BKD (BB * KK * DIN)         // 1536
#define BKDN (BKD * NN)             // 24576 scan states
#define LOG2E 1.442695040888963f

// direction index maps: pos_k(l) gives the hw-position visited at scan step l
__device__ __forceinline__ int pos_k(int k, int l) {
    switch (k) {
        case 0: return l;
        case 1: return ((l & 63) << 6) | (l >> 6);
        case 2: return 4095 - l;
        default: { int s = 4095 - l; return ((s & 63) << 6) | (s >> 6); }
    }
}

// ---------------- Kernel A: in_proj GEMM ----------------
__global__ __launch_bounds__(256) void k_inproj(const float* __restrict__ x,
                                                const float* __restrict__ W,
                                                float* __restrict__ xc_raw,
                                                float* __restrict__ zbuf) {
    __shared__ float xs[32][DMOD];
    int row0 = blockIdx.x * 32;
    int tid = threadIdx.x;
    for (int i = tid; i < 32 * DMOD; i += 256) {
        xs[i / DMOD][i % DMOD] = x[(size_t)row0 * DMOD + i];
    }
    __syncthreads();
    for (int c = tid; c < 2 * DIN; c += 256) {
        const float* w = W + (size_t)c * DMOD;
        float acc[32];
#pragma unroll
        for (int i = 0; i < 32; i++) acc[i] = 0.f;
        for (int j = 0; j < DMOD; j++) {
            float wv = w[j];
#pragma unroll
            for (int i = 0; i < 32; i++) acc[i] += xs[i][j] * wv;
        }
#pragma unroll
        for (int i = 0; i < 32; i++) {
            int row = row0 + i;
            if (c < DIN) xc_raw[(size_t)row * DIN + c] = acc[i];
            else         zbuf[(size_t)row * DIN + (c - DIN)] = acc[i];
        }
    }
}

// ---------------- Kernel B: depthwise 3x3 conv + bias + SiLU (float4) ----------------
// thread per (b,l,d4): 4 channels each
__global__ __launch_bounds__(256) void k_conv(const float* __restrict__ xc_raw,
                                              const float* __restrict__ cw,
                                              const float* __restrict__ cb,
                                              float* __restrict__ xc_l) {
    __shared__ float cwt[9][DIN];
    __shared__ float cbs[DIN];
    int t = threadIdx.x;
    for (int i = t; i < 9 * DIN; i += 256) {
        int d = i / 9, tap = i % 9;          // read cw coalesced, scatter to cwt
        cwt[tap][d] = cw[i];
    }
    if (t < DIN) cbs[t] = cb[t];
    __syncthreads();

    int gid = blockIdx.x * 256 + t;          // B*L*48
    if (gid >= BB * LL * 48) return;
    int d4 = gid % 48;
    int l = (gid / 48) % LL;
    int b = gid / (48 * LL);
    int h = l >> 6, w = l & 63;
    int d = d4 * 4;

    float4 acc = *(const float4*)(cbs + d);
#pragma unroll
    for (int dh = -1; dh <= 1; dh++) {
        int hh = h + dh;
        if ((unsigned)hh >= HH) continue;
#pragma unroll
        for (int dw2 = -1; dw2 <= 1; dw2++) {
            int ww2 = w + dw2;
            if ((unsigned)ww2 >= WW) continue;
            float4 xv = *(const float4*)(xc_raw + ((size_t)b * LL + hh * 64 + ww2) * DIN + d);
            float4 wv = *(const float4*)(&cwt[(dh + 1) * 3 + (dw2 + 1)][d]);
            acc.x += xv.x * wv.x; acc.y += xv.y * wv.y;
            acc.z += xv.z * wv.z; acc.w += xv.w * wv.w;
        }
    }
    float4 r;
    r.x = acc.x / (1.f + __expf(-acc.x));
    r.y = acc.y / (1.f + __expf(-acc.y));
    r.z = acc.z / (1.f + __expf(-acc.z));
    r.w = acc.w / (1.f + __expf(-acc.w));
    *(float4*)(xc_l + ((size_t)b * LL + l) * DIN + d) = r;
}

// ---------------- Kernel C: x_proj GEMM tile + fused dt_proj + softplus ----------------
__global__ __launch_bounds__(192) void k_xproj(const float* __restrict__ xc_l,
                                               const float* __restrict__ xpw,   // (K,38,192)
                                               const float* __restrict__ dtw,   // (K,192,6)
                                               const float* __restrict__ dtb,   // (K,192)
                                               float* __restrict__ delta,       // (bk,l,192)
                                               float* __restrict__ Bsb,         // (bk,l,16)
                                               float* __restrict__ Csb) {       // (bk,l,16)
    __shared__ float xs[32][193];
    __shared__ float cvs[38 * 33];

    int tile = blockIdx.x & 127;
    int k = (blockIdx.x >> 7) & 3;
    int b = blockIdx.x >> 9;
    int bk = b * KK + k;
    int l0 = tile * 32;
    int t = threadIdx.x;

    for (int i = 0; i < 32; i++) {
        int lp = pos_k(k, l0 + i);
        xs[i][t] = xc_l[((size_t)b * LL + lp) * DIN + t];
    }
    __syncthreads();

    {
        int rg = t / 48;          // 0..3
        int c = t % 48;           // active c<38
        if (c < 38) {
            const float* w = xpw + ((size_t)k * 38 + c) * DIN;
            int i0 = rg * 8;
            float acc[8];
#pragma unroll
            for (int r = 0; r < 8; r++) acc[r] = 0.f;
            for (int j = 0; j < DIN; j++) {
                float wv = w[j];
#pragma unroll
                for (int r = 0; r < 8; r++) acc[r] += xs[i0 + r][j] * wv;
            }
#pragma unroll
            for (int r = 0; r < 8; r++) cvs[c * 33 + i0 + r] = acc[r];
        }
    }
    __syncthreads();

    for (int idx = t; idx < 512; idx += 192) {
        int i = idx >> 4, n = idx & 15;
        size_t o = ((size_t)bk * LL + (l0 + i)) * NN + n;
        Bsb[o] = cvs[(6 + n) * 33 + i];
        Csb[o] = cvs[(22 + n) * 33 + i];
    }

    {
        const float* dwp = dtw + ((size_t)k * DIN + t) * RR;
        float dw0 = dwp[0], dw1 = dwp[1], dw2 = dwp[2],
              dw3 = dwp[3], dw4 = dwp[4], dw5 = dwp[5];
        float bias = dtb[k * DIN + t];
        for (int i = 0; i < 32; i++) {
            float v = bias + cvs[0 * 33 + i] * dw0 + cvs[1 * 33 + i] * dw1 +
                      cvs[2 * 33 + i] * dw2 + cvs[3 * 33 + i] * dw3 +
                      cvs[4 * 33 + i] * dw4 + cvs[5 * 33 + i] * dw5;
            float sp = (v > 20.f) ? v : __logf(1.f + __expf(v));
            delta[((size_t)bk * LL + (l0 + i)) * DIN + t] = sp;
        }
    }
}

// ---------------- Kernel D1: per-chunk local scan, 16 states/thread ----------------
__global__ __launch_bounds__(192) void k_scan1(const float* __restrict__ delta,
                                               const float* __restrict__ Bsb,
                                               const float* __restrict__ xc_l,
                                               const float* __restrict__ A_logs,
                                               float* __restrict__ Sbuf,   // (NC, BKD)
                                               float* __restrict__ Ebuf) { // (NC, BKDN)
    __shared__ float4 Bs4[CL][4];
    int c = blockIdx.x % NC;
    int bk = blockIdx.x / NC;
    int k = bk % KK;
    int b = bk / KK;
    int t = threadIdx.x;                 // d

    {
        const float4* src = (const float4*)(Bsb + ((size_t)bk * LL + c * CL) * NN);
        if (t < CL * 4) ((float4*)Bs4)[t] = src[t];
    }

    float An[NN];   // pre-scaled by log2(e): dA = exp2(dv*An)
    {
        const float4* ap = (const float4*)(A_logs + ((size_t)(k * DIN + t)) * NN);
#pragma unroll
        for (int q = 0; q < 4; q++) {
            float4 a4 = ap[q];
            An[q * 4 + 0] = -__expf(a4.x) * LOG2E;
            An[q * 4 + 1] = -__expf(a4.y) * LOG2E;
            An[q * 4 + 2] = -__expf(a4.z) * LOG2E;
            An[q * 4 + 3] = -__expf(a4.w) * LOG2E;
        }
    }
    __syncthreads();

    const float* dp = delta + ((size_t)bk * LL + c * CL) * DIN + t;
    const float* up = xc_l + (size_t)b * LL * DIN + t;
    int l0 = c * CL;

    float h[NN];
#pragma unroll
    for (int n = 0; n < NN; n++) h[n] = 0.f;
    float S = 0.f;

    float dv = dp[0];
    float u  = up[(size_t)pos_k(k, l0) * DIN];
    for (int li = 0; li < CL; li++) {
        int ln = (li + 1 < CL) ? li + 1 : li;
        float dvn = dp[(size_t)ln * DIN];
        float un  = up[(size_t)pos_k(k, l0 + ln) * DIN];
        S += dv;
        float du = dv * u;
#pragma unroll
        for (int q = 0; q < 4; q++) {
            float4 Bq = Bs4[li][q];
            h[q*4+0] = exp2f(dv * An[q*4+0]) * h[q*4+0] + du * Bq.x;
            h[q*4+1] = exp2f(dv * An[q*4+1]) * h[q*4+1] + du * Bq.y;
            h[q*4+2] = exp2f(dv * An[q*4+2]) * h[q*4+2] + du * Bq.z;
            h[q*4+3] = exp2f(dv * An[q*4+3]) * h[q*4+3] + du * Bq.w;
        }
        dv = dvn; u = un;
    }

    Sbuf[(size_t)c * BKD + bk * DIN + t] = S;
    float4* eo = (float4*)(Ebuf + (size_t)c * BKDN + ((size_t)(bk * DIN + t)) * NN);
#pragma unroll
    for (int q = 0; q < 4; q++) {
        float4 v;
        v.x = h[q*4+0]; v.y = h[q*4+1]; v.z = h[q*4+2]; v.w = h[q*4+3];
        eo[q] = v;
    }
}

// ---------------- Kernel D2: inter-chunk recurrence (thread per state) ----------------
__global__ __launch_bounds__(256) void k_scan2(const float* __restrict__ Sbuf,
                                               const float* __restrict__ A_logs,
                                               float* __restrict__ Ebuf) {
    int gid = blockIdx.x * 256 + threadIdx.x;
    if (gid >= BKDN) return;
    int bkd = gid >> 4;
    int n = gid & 15;
    int d = bkd % DIN;
    int k = (bkd / DIN) % KK;
    float An = -__expf(A_logs[((size_t)(k * DIN + d)) * NN + n]) * LOG2E;
    float h = 0.f;
    for (int c = 0; c < NC; c++) {
        float S = Sbuf[(size_t)c * BKD + bkd];
        float P = exp2f(An * S);
        size_t o = (size_t)c * BKDN + gid;
        float e = Ebuf[o];
        Ebuf[o] = h;          // true initial state entering chunk c
        h = P * h + e;
    }
}

// ---------------- Kernel D3: per-chunk rescan + y (in place over delta) ----------------
__global__ __launch_bounds__(192) void k_scan3(float* __restrict__ delta,    // in: delta, out: y
                                               const float* __restrict__ Bsb,
                                               const float* __restrict__ Csb,
                                               const float* __restrict__ xc_l,
                                               const float* __restrict__ A_logs,
                                               const float* __restrict__ Ebuf) {
    __shared__ float4 Bs4[CL][4];
    __shared__ float4 Cs4[CL][4];
    int c = blockIdx.x % NC;
    int bk = blockIdx.x / NC;
    int k = bk % KK;
    int b = bk / KK;
    int t = threadIdx.x;

    {
        const float4* srcB = (const float4*)(Bsb + ((size_t)bk * LL + c * CL) * NN);
        const float4* srcC = (const float4*)(Csb + ((size_t)bk * LL + c * CL) * NN);
        if (t < CL * 4) {
            ((float4*)Bs4)[t] = srcB[t];
            ((float4*)Cs4)[t] = srcC[t];
        }
    }

    float An[NN];   // pre-scaled by log2(e)
    {
        const float4* ap = (const float4*)(A_logs + ((size_t)(k * DIN + t)) * NN);
#pragma unroll
        for (int q = 0; q < 4; q++) {
            float4 a4 = ap[q];
            An[q * 4 + 0] = -__expf(a4.x) * LOG2E;
            An[q * 4 + 1] = -__expf(a4.y) * LOG2E;
            An[q * 4 + 2] = -__expf(a4.z) * LOG2E;
            An[q * 4 + 3] = -__expf(a4.w) * LOG2E;
        }
    }

    float h[NN];
    {
        const float4* ei = (const float4*)(Ebuf + (size_t)c * BKDN + ((size_t)(bk * DIN + t)) * NN);
#pragma unroll
        for (int q = 0; q < 4; q++) {
            float4 v = ei[q];
            h[q*4+0] = v.x; h[q*4+1] = v.y; h[q*4+2] = v.z; h[q*4+3] = v.w;
        }
    }
    __syncthreads();

    float* dp = delta + ((size_t)bk * LL + c * CL) * DIN + t;
    const float* up = xc_l + (size_t)b * LL * DIN + t;
    int l0 = c * CL;

    float dv = dp[0];
    float u  = up[(size_t)pos_k(k, l0) * DIN];
    for (int li = 0; li < CL; li++) {
        int ln = (li + 1 < CL) ? li + 1 : li;
        float dvn = dp[(size_t)ln * DIN];
        float un  = up[(size_t)pos_k(k, l0 + ln) * DIN];
        float du = dv * u;
        float p = 0.f;
#pragma unroll
        for (int q = 0; q < 4; q++) {
            float4 Bq = Bs4[li][q];
            float4 Cq = Cs4[li][q];
            h[q*4+0] = exp2f(dv * An[q*4+0]) * h[q*4+0] + du * Bq.x;
            h[q*4+1] = exp2f(dv * An[q*4+1]) * h[q*4+1] + du * Bq.y;
            h[q*4+2] = exp2f(dv * An[q*4+2]) * h[q*4+2] + du * Bq.z;
            h[q*4+3] = exp2f(dv * An[q*4+3]) * h[q*4+3] + du * Bq.w;
            p += h[q*4+0] * Cq.x + h[q*4+1] * Cq.y + h[q*4+2] * Cq.z + h[q*4+3] * Cq.w;
        }
        dp[(size_t)li * DIN] = p;      // y over delta
        dv = dvn; u = un;
    }
}

// ---------------- Kernel E: merge + LN + SiLU(z) gate + out_proj, 16-row tiles ----------------
// grid = B*L/16 = 512 blocks x 256 threads; thread = (row = t>>4, seg = t&15)
__global__ __launch_bounds__(256) void k_out(const float* __restrict__ y_dir,
                                             const float* __restrict__ xc_l,
                                             const float* __restrict__ zbuf,
                                             const float* __restrict__ Ds,
                                             const float* __restrict__ g,
                                             const float* __restrict__ be,
                                             const float* __restrict__ Wout,
                                             float* __restrict__ out) {
    __shared__ float yn[16][196];     // pad 196: float4-aligned, rows offset 4 banks
    __shared__ float dsum[DIN];

    int blk = blockIdx.x;
    int b = blk >> 8;                 // 256 tiles per batch
    int hw0 = (blk & 255) * 16;
    int t = threadIdx.x;
    int row = t >> 4;
    int seg = t & 15;
    int hw = hw0 + row;

    if (t < DIN) dsum[t] = Ds[t] + Ds[DIN + t] + Ds[2 * DIN + t] + Ds[3 * DIN + t];
    __syncthreads();

    // direction positions for this row
    int lp1 = ((hw & 63) << 6) | (hw >> 6);
    int lp2 = 4095 - hw;
    int lp3 = ((lp2 & 63) << 6) | (lp2 >> 6);
    const float* y0 = y_dir + ((size_t)(b * KK + 0) * LL + hw)  * DIN;
    const float* y1 = y_dir + ((size_t)(b * KK + 1) * LL + lp1) * DIN;
    const float* y2 = y_dir + ((size_t)(b * KK + 2) * LL + lp2) * DIN;
    const float* y3 = y_dir + ((size_t)(b * KK + 3) * LL + lp3) * DIN;
    const float* xr = xc_l + ((size_t)b * LL + hw) * DIN;

    // merge + LN partial sums in one pass (each thread: 12 d's of its row)
    float s = 0.f, s2 = 0.f;
#pragma unroll
    for (int j = 0; j < 12; j++) {
        int d = seg + 16 * j;
        float a = y0[d] + y1[d] + y2[d] + y3[d] + dsum[d] * xr[d];
        yn[row][d] = a;
        s += a; s2 += a * a;
    }
    // 16-lane group reduce (same row)
#pragma unroll
    for (int o = 1; o < 16; o <<= 1) {
        s  += __shfl_xor(s, o, 64);
        s2 += __shfl_xor(s2, o, 64);
    }
    float mean = s * (1.f / DIN);
    float var = s2 * (1.f / DIN) - mean * mean;
    float rstd = rsqrtf(var + 1e-5f);

    const float* zr = zbuf + ((size_t)b * LL + hw) * DIN;
#pragma unroll
    for (int j = 0; j < 12; j++) {
        int d = seg + 16 * j;
        float yv = (yn[row][d] - mean) * rstd * g[d] + be[d];
        float zv = zr[d];
        yn[row][d] = yv * zv / (1.f + __expf(-zv));
    }
    __syncthreads();

    // out_proj: thread -> (row = t>>4, cbase = t&15), 6 cols each (c = cbase+16*ci)
    int cbase = seg;
    float acc[6] = {0.f, 0.f, 0.f, 0.f, 0.f, 0.f};
    const float4* yrow4 = (const float4*)&yn[row][0];
    for (int jc = 0; jc < 48; jc++) {
        float4 y4 = yrow4[jc];                 // broadcast: 4 distinct addrs/wave
#pragma unroll
        for (int ci = 0; ci < 6; ci++) {
            const float4* w4 = (const float4*)(Wout + (size_t)(cbase + 16 * ci) * DIN);
            float4 w = w4[jc];
            acc[ci] += y4.x * w.x + y4.y * w.y + y4.z * w.z + y4.w * w.w;
        }
    }
    size_t ob = ((size_t)b * LL + hw) * DMOD;
#pragma unroll
    for (int ci = 0; ci < 6; ci++) out[ob + cbase + 16 * ci] = acc[ci];
}

extern "C" void kernel_launch(void* const* d_in, const int* in_sizes, int n_in,
                              void* d_out, int out_size, void* d_ws, size_t ws_size,
                              hipStream_t stream) {
    const float* x        = (const float*)d_in[0];
    const float* in_proj_w= (const float*)d_in[1];
    const float* conv_w   = (const float*)d_in[2];
    const float* conv_b   = (const float*)d_in[3];
    const float* x_proj_w = (const float*)d_in[4];
    const float* dt_proj_w= (const float*)d_in[5];
    const float* dt_proj_b= (const float*)d_in[6];
    const float* A_logs   = (const float*)d_in[7];
    const float* Ds       = (const float*)d_in[8];
    const float* out_g    = (const float*)d_in[9];
    const float* out_b    = (const float*)d_in[10];
    const float* out_proj_w=(const float*)d_in[11];
    float* out = (float*)d_out;

    float* ws = (float*)d_ws;
    const size_t BL = (size_t)BB * LL;                    // 8192
    float* xc_raw = ws;                                   // BL*192
    float* zbuf   = xc_raw + BL * DIN;                    // BL*192
    float* xc_l   = zbuf + BL * DIN;                      // BL*192
    float* delta  = xc_l + BL * DIN;                      // B*K*L*192 (becomes y)
    float* Bsb    = delta + (size_t)BB * KK * LL * DIN;   // B*K*L*16
    float* Csb    = Bsb + (size_t)BB * KK * LL * NN;      // B*K*L*16
    float* Ebuf   = Csb + (size_t)BB * KK * LL * NN;      // NC*BKDN
    float* Sbuf   = Ebuf + (size_t)NC * BKDN;             // NC*BKD

    k_inproj<<<BL / 32, 256, 0, stream>>>(x, in_proj_w, xc_raw, zbuf);
    k_conv<<<(BB * LL * 48 + 255) / 256, 256, 0, stream>>>(xc_raw, conv_w, conv_b, xc_l);
    k_xproj<<<BB * KK * (LL / 32), 192, 0, stream>>>(xc_l, x_proj_w, dt_proj_w, dt_proj_b,
                                                     delta, Bsb, Csb);
    k_scan1<<<BB * KK * NC, 192, 0, stream>>>(delta, Bsb, xc_l, A_logs, Sbuf, Ebuf);
    k_scan2<<<(BKDN + 255) / 256, 256, 0, stream>>>(Sbuf, A_logs, Ebuf);
    k_scan3<<<BB * KK * NC, 192, 0, stream>>>(delta, Bsb, Csb, xc_l, A_logs, Ebuf);
    k_out<<<(BB * LL) / 16, 256, 0, stream>>>(delta, xc_l, zbuf, Ds, out_g, out_b, out_proj_w, out);
}